// Round 10
// baseline (91.702 us; speedup 1.0000x reference)
//
#include <hip/hip_runtime.h>
#include <math.h>

typedef float f32x4 __attribute__((ext_vector_type(4)));
typedef short s16x8 __attribute__((ext_vector_type(8)));

#define NROWS 8192
#define NCOLS 512
#define BHALF 4096
#define NT    64       // 8192 / 128 tiles per dim
#define BM    128
#define BK    32
#define NKT   (NCOLS / BK)          // 16 K-steps
#define NBLK  (NT * (NT + 1) / 2)   // 2080 triangular tiles (2080 % 8 == 0)
#define CSPART 256                   // colsum partial blocks

typedef __attribute__((address_space(1))) const unsigned int guint;
typedef __attribute__((address_space(3))) unsigned int luint;

// ---------- helpers ----------
__device__ __forceinline__ unsigned short f2bf(float f) {
    // RNE float -> bf16 (inputs are finite normals; no NaN handling needed)
    unsigned u = __builtin_bit_cast(unsigned, f);
    u += 0x7FFFu + ((u >> 16) & 1u);
    return (unsigned short)(u >> 16);
}

// ---------- fused conversion + row-sq + colsum partials ----------
// 256 blocks x 256 threads; block covers 32 rows (8 rows per wave).
// Deterministic: all reductions fixed-order, no atomics.
__global__ void k_conv(const float* __restrict__ src, const float* __restrict__ tgt,
                       short* __restrict__ bfall, float* __restrict__ sq,
                       float* __restrict__ cspart) {
    __shared__ float colp[4][NCOLS];
    int t = threadIdx.x, w = t >> 6, l = t & 63;
    int r0 = blockIdx.x * 32 + w * 8;
    float c0x=0.f,c0y=0.f,c0z=0.f,c0w=0.f, c1x=0.f,c1y=0.f,c1z=0.f,c1w=0.f;
    #pragma unroll
    for (int r = 0; r < 8; ++r) {
        int row = r0 + r;
        const float* base = (row < BHALF) ? (src + (size_t)row * NCOLS)
                                          : (tgt + (size_t)(row - BHALF) * NCOLS);
        float4 a = ((const float4*)base)[2 * l];
        float4 b = ((const float4*)base)[2 * l + 1];
        s16x8 v;
        v[0] = (short)f2bf(a.x); v[1] = (short)f2bf(a.y);
        v[2] = (short)f2bf(a.z); v[3] = (short)f2bf(a.w);
        v[4] = (short)f2bf(b.x); v[5] = (short)f2bf(b.y);
        v[6] = (short)f2bf(b.z); v[7] = (short)f2bf(b.w);
        ((s16x8*)(bfall + (size_t)row * NCOLS))[l] = v;
        float s = a.x*a.x + a.y*a.y + a.z*a.z + a.w*a.w
                + b.x*b.x + b.y*b.y + b.z*b.z + b.w*b.w;
        #pragma unroll
        for (int o = 32; o > 0; o >>= 1) s += __shfl_down(s, o);
        if (l == 0) sq[row] = s;
        c0x += a.x; c0y += a.y; c0z += a.z; c0w += a.w;
        c1x += b.x; c1y += b.y; c1z += b.z; c1w += b.w;
    }
    colp[w][l*8+0] = c0x; colp[w][l*8+1] = c0y; colp[w][l*8+2] = c0z; colp[w][l*8+3] = c0w;
    colp[w][l*8+4] = c1x; colp[w][l*8+5] = c1y; colp[w][l*8+6] = c1z; colp[w][l*8+7] = c1w;
    __syncthreads();
    float s0 = colp[0][t] + colp[1][t] + colp[2][t] + colp[3][t];
    float s1 = colp[0][t+256] + colp[1][t+256] + colp[2][t+256] + colp[3][t+256];
    cspart[(size_t)blockIdx.x * NCOLS + t]       = s0;
    cspart[(size_t)blockIdx.x * NCOLS + t + 256] = s1;
}

// bandwidth from analytic sum(l2) = 2n*T - 2*||colsum||^2 ; store log2(e)/bw_k.
// 1024 threads, independent accumulator chains, fixed-order -> deterministic.
__global__ void k_bw(const float* __restrict__ sq, const float* __restrict__ cspart,
                     float* __restrict__ cvals) {
    __shared__ double red[1024];
    int t = threadIdx.x;
    // phase 1: sum of sq (8 independent loads per thread)
    double a = 0.0;
    #pragma unroll
    for (int i = 0; i < 8; ++i) a += (double)sq[t + i * 1024];
    red[t] = a; __syncthreads();
    for (int o = 512; o > 0; o >>= 1) { if (t < o) red[t] += red[t + o]; __syncthreads(); }
    double sT = red[0];
    __syncthreads();
    // phase 2: colsum over 256 partials; thread t: col c = t&511, half h = t>>9
    int c = t & 511, h = t >> 9;
    double d0 = 0.0, d1 = 0.0, d2 = 0.0, d3 = 0.0;
    int p0 = h * 128;
    #pragma unroll 8
    for (int p = 0; p < 128; p += 4) {
        d0 += (double)cspart[(size_t)(p0 + p + 0) * NCOLS + c];
        d1 += (double)cspart[(size_t)(p0 + p + 1) * NCOLS + c];
        d2 += (double)cspart[(size_t)(p0 + p + 2) * NCOLS + c];
        d3 += (double)cspart[(size_t)(p0 + p + 3) * NCOLS + c];
    }
    red[t] = (d0 + d1) + (d2 + d3);
    __syncthreads();
    double v = 0.0;
    if (t < 512) { double cs = red[t] + red[t + 512]; v = cs * cs; }
    __syncthreads();
    red[t] = v; __syncthreads();
    for (int o = 512; o > 0; o >>= 1) { if (t < o) red[t] += red[t + o]; __syncthreads(); }
    if (t == 0) {
        double G = red[0];
        double sum_l2 = 2.0 * (double)NROWS * sT - 2.0 * G;
        double denom = (double)NROWS * (double)NROWS - (double)NROWS;
        double bw = sum_l2 / denom / 4.0;   // KERNEL_MUL^(KERNEL_NUM/2) = 4
        const double L2E = 1.4426950408889634;
        double b = bw;
        #pragma unroll
        for (int k = 0; k < 5; ++k) { cvals[k] = (float)(L2E / b); b *= 2.0; }
    }
}

// ---------- main fused MMD kernel ----------
// R9 skeleton (counted vmcnt, vmcnt->barrier->stage->compute, hoisted addressing)
// + register double-buffering: 4 LDS buffers, prefetch distance 3, so vmcnt(4)
// certifies tile kt AND kt+1; each step PRELOADs kt+1's fragments into the
// alternate reg set while MFMAs run on the current set -> ds_read latency
// hidden under MFMA. Static P/Q alternation (no runtime indexing).
// Buffer safety: STAGE(kt+3) overwrites buffer preloaded at step kt-2,
// consumed at step kt-1 -> two barriers in between.
__global__ __launch_bounds__(256, 2)
void k_mmd(const short* __restrict__ bfall, const float* __restrict__ sq,
           const float* __restrict__ cvals, double* __restrict__ psum) {
    __shared__ short As[4][BM * BK];   // 4 x 8 KB
    __shared__ short Bs[4][BM * BK];   // 4 x 8 KB
    __shared__ float wred[4];

    // T1: XCD-aware bijective swizzle (NBLK = 8*260), then triangular decode
    int bid = blockIdx.x;
    int swz = (bid & 7) * (NBLK / 8) + (bid >> 3);
    int rem = swz;
    int ti = 0;
    while (rem >= NT - ti) { rem -= NT - ti; ++ti; }
    int tj = ti + rem;

    const int t  = threadIdx.x;
    const int w  = t >> 6;       // wave 0..3
    const int l  = t & 63;
    const int wr = w >> 1, wc = w & 1;
    const int lr = l & 15;       // fragment row/col lane
    const int lk = l >> 4;       // 0..3 k-group (8 bf16 = 1 slot each)

    const int rowA0 = ti * BM, rowB0 = tj * BM;
    const short* gA = bfall + (size_t)rowA0 * NCOLS;
    const short* gB = bfall + (size_t)rowB0 * NCOLS;

    // ---- hoisted staging addresses (kt folds into the global ptr as imm) ----
    const int q0 = t, q1 = 256 + t;
    const int row0 = q0 >> 2, ss0 = (q0 & 3) ^ ((row0 >> 1) & 3);
    const int row1 = q1 >> 2, ss1 = (q1 & 3) ^ ((row1 >> 1) & 3);
    const short* ga0 = gA + (size_t)row0 * NCOLS + ss0 * 8;
    const short* ga1 = gA + (size_t)row1 * NCOLS + ss1 * 8;
    const short* gb0 = gB + (size_t)row0 * NCOLS + ss0 * 8;
    const short* gb1 = gB + (size_t)row1 * NCOLS + ss1 * 8;
    char* dA = (char*)As + q0 * 16;      // dest for q0; q1 dest = dA + 4096
    char* dB = (char*)Bs + q0 * 16;

    // ---- hoisted compute addresses (bsel/m enter as const imm) ----
    const int ssl  = lk ^ ((lr >> 1) & 3);
    const char* pA = (const char*)As + (wr * 64 + lr) * 64 + ssl * 16;
    const char* pB = (const char*)Bs + (wc * 64 + lr) * 64 + ssl * 16;

    // stage tile kt into buffer bsel: 4 global_load_lds per wave -> vmcnt +4
    #define STAGE(bsel, kt)                                                        \
        __builtin_amdgcn_global_load_lds((guint*)(ga0 + (kt) * BK),                \
            (luint*)(dA + (bsel) * 8192), 16, 0, 0);                               \
        __builtin_amdgcn_global_load_lds((guint*)(ga1 + (kt) * BK),                \
            (luint*)(dA + (bsel) * 8192 + 4096), 16, 0, 0);                        \
        __builtin_amdgcn_global_load_lds((guint*)(gb0 + (kt) * BK),                \
            (luint*)(dB + (bsel) * 8192), 16, 0, 0);                               \
        __builtin_amdgcn_global_load_lds((guint*)(gb1 + (kt) * BK),                \
            (luint*)(dB + (bsel) * 8192 + 4096), 16, 0, 0);

    // preload the 8 fragments of buffer bsel into reg set (afX, bfX)
    #define PRELOAD(afX, bfX, bsel)                                                \
        _Pragma("unroll")                                                          \
        for (int m = 0; m < 4; ++m)                                                \
            afX[m] = *(const s16x8*)(pA + (bsel) * 8192 + m * 1024);               \
        _Pragma("unroll")                                                          \
        for (int n = 0; n < 4; ++n)                                                \
            bfX[n] = *(const s16x8*)(pB + (bsel) * 8192 + n * 1024);

    // 16 MFMAs on a reg set
    #define COMPUTE(afX, bfX)                                                      \
        __builtin_amdgcn_s_setprio(1);                                             \
        _Pragma("unroll")                                                          \
        for (int m = 0; m < 4; ++m)                                                \
            _Pragma("unroll")                                                      \
            for (int n = 0; n < 4; ++n)                                            \
                acc[m][n] = __builtin_amdgcn_mfma_f32_16x16x32_bf16(               \
                    afX[m], bfX[n], acc[m][n], 0, 0, 0);                           \
        __builtin_amdgcn_s_setprio(0);

    // step kt: vmcnt certifies tiles kt AND kt+1 landed (prefetch dist 3,
    // only tile kt+2's 4 loads may remain in flight); barrier; issue stage
    // kt+3; preload kt+1's fragments (overlaps with MFMAs of kt).
    #define STEP(kt, vm, afU, bfU, afL, bfL)                                       \
        asm volatile("s_waitcnt vmcnt(" #vm ")" ::: "memory");                     \
        __builtin_amdgcn_s_barrier();                                              \
        asm volatile("" ::: "memory");                                             \
        if ((kt) + 3 < NKT) { STAGE(((kt) + 3) & 3, (kt) + 3) }                    \
        if ((kt) + 1 < NKT) { PRELOAD(afL, bfL, ((kt) + 1) & 3) }                  \
        COMPUTE(afU, bfU)

    f32x4 acc[4][4] = {};
    s16x8 afP[4], bfP[4], afQ[4], bfQ[4];

    STAGE(0, 0) STAGE(1, 1) STAGE(2, 2)      // 12 loads in flight
    asm volatile("s_waitcnt vmcnt(8)" ::: "memory");   // tile 0 landed
    __builtin_amdgcn_s_barrier();
    asm volatile("" ::: "memory");
    PRELOAD(afP, bfP, 0)

    STEP(0, 4, afP, bfP, afQ, bfQ)   STEP(1, 4, afQ, bfQ, afP, bfP)
    STEP(2, 4, afP, bfP, afQ, bfQ)   STEP(3, 4, afQ, bfQ, afP, bfP)
    STEP(4, 4, afP, bfP, afQ, bfQ)   STEP(5, 4, afQ, bfQ, afP, bfP)
    STEP(6, 4, afP, bfP, afQ, bfQ)   STEP(7, 4, afQ, bfQ, afP, bfP)
    STEP(8, 4, afP, bfP, afQ, bfQ)   STEP(9, 4, afQ, bfQ, afP, bfP)
    STEP(10, 4, afP, bfP, afQ, bfQ)  STEP(11, 4, afQ, bfQ, afP, bfP)
    STEP(12, 4, afP, bfP, afQ, bfQ)  STEP(13, 4, afQ, bfQ, afP, bfP)
    STEP(14, 0, afP, bfP, afQ, bfQ)  STEP(15, 0, afQ, bfQ, afP, bfP)

    #undef STAGE
    #undef PRELOAD
    #undef COMPUTE
    #undef STEP

    // ---------- epilogue: l2 -> exp square-chain -> signed/weighted sum ----------
    // (global loads kept AFTER the K-loop so they don't perturb vmcnt counts)
    f32x4 sqa[4];
    #pragma unroll
    for (int m = 0; m < 4; ++m)
        sqa[m] = *(const f32x4*)&sq[rowA0 + wr * 64 + m * 16 + lk * 4];
    float sqb[4];
    #pragma unroll
    for (int n = 0; n < 4; ++n)
        sqb[n] = sq[rowB0 + wc * 64 + n * 16 + lr];
    float c4 = cvals[4];

    const bool diag = (ti == tj);
    const float sgn = ((rowA0 < BHALF) == (rowB0 < BHALF)) ? 1.f : -1.f;
    float local = 0.f;
    #pragma unroll
    for (int m = 0; m < 4; ++m)
        #pragma unroll
        for (int n = 0; n < 4; ++n)
            #pragma unroll
            for (int r = 0; r < 4; ++r) {
                float d  = acc[m][n][r];
                float l2 = sqa[m][r] + sqb[n] - 2.f * d;
                // e_k = exp(-l2/(bw*2^k)) = x^(2^(4-k)), x = 2^(-l2*c4)
                float x  = exp2f(-l2 * c4);
                float x2 = x * x;
                float x4 = x2 * x2;
                float x8 = x4 * x4;
                float e  = x + x2 + x4 + x8 + x8 * x8;
                if (diag) {
                    int gi = rowA0 + wr * 64 + m * 16 + lk * 4 + r;
                    int gj = rowB0 + wc * 64 + n * 16 + lr;
                    float wgt = (gj > gi) ? 2.f : ((gj == gi) ? 1.f : 0.f);
                    local += wgt * e;
                } else {
                    local += e;
                }
            }
    if (!diag) local *= 2.f * sgn;   // diagonal tiles always sgn=+1

    #pragma unroll
    for (int o = 32; o > 0; o >>= 1) local += __shfl_down(local, o);
    if (l == 0) wred[w] = local;
    __syncthreads();
    if (t == 0) {
        psum[blockIdx.x] = (double)(wred[0] + wred[1] + wred[2] + wred[3]);
    }
}

// fixed-order final reduction over NBLK partials -> loss
__global__ void k_final(const double* __restrict__ psum, float* __restrict__ out) {
    __shared__ double red[256];
    int t = threadIdx.x;
    double a = 0.0;
    for (int i = t; i < NBLK; i += 256) a += psum[i];
    red[t] = a; __syncthreads();
    for (int o = 128; o > 0; o >>= 1) { if (t < o) red[t] += red[t + o]; __syncthreads(); }
    if (t == 0) out[0] = (float)(red[0] * (1.0 / ((double)BHALF * (double)BHALF)));
}

// ---------- launch ----------
extern "C" void kernel_launch(void* const* d_in, const int* in_sizes, int n_in,
                              void* d_out, int out_size, void* d_ws, size_t ws_size,
                              hipStream_t stream) {
    (void)in_sizes; (void)n_in; (void)out_size; (void)ws_size;
    const float* src = (const float*)d_in[0];
    const float* tgt = (const float*)d_in[1];
    float* out = (float*)d_out;
    char* ws = (char*)d_ws;
    // layout (all offsets 16B-aligned; every consumed word is rewritten each call):
    short*  bfall  = (short*) (ws);                      // 8192*512*2 = 8388608 B
    float*  sq     = (float*) (ws + 8388608);            // 8192*4 = 32768 B
    float*  cspart = (float*) (ws + 8388608 + 32768);    // 256*512*4 = 524288 B
    float*  cvals  = (float*) (ws + 8388608 + 32768 + 524288);        // 20 B
    double* psum   = (double*)(ws + 8388608 + 32768 + 524288 + 32);   // 2080*8 = 16640 B

    k_conv  <<<CSPART, 256, 0, stream>>>(src, tgt, bfall, sq, cspart);
    k_bw    <<<1, 1024, 0, stream>>>(sq, cspart, cvals);
    k_mmd   <<<NBLK, 256, 0, stream>>>(bfall, sq, cvals, psum);
    k_final <<<1, 256, 0, stream>>>(psum, out);
}

// Round 11
// 86.219 us; speedup vs baseline: 1.0636x; 1.0636x over previous
//
#include <hip/hip_runtime.h>
#include <math.h>

typedef float f32x4 __attribute__((ext_vector_type(4)));
typedef short s16x8 __attribute__((ext_vector_type(8)));

#define NROWS 8192
#define NCOLS 512
#define BHALF 4096
#define BM    256      // A rows per tile
#define BN    128      // B rows (output cols) per tile
#define BK    32
#define NKT   (NCOLS / BK)          // 16 K-steps
#define NTI   32       // 8192 / BM
#define NTJ   64       // 8192 / BN
#define NBLK  1056     // sum_{ti<32}(64-2*ti) ; 1056 % 8 == 0
#define CSPART 256     // colsum partial blocks

typedef __attribute__((address_space(1))) const unsigned int guint;
typedef __attribute__((address_space(3))) unsigned int luint;

// ---------- helpers ----------
__device__ __forceinline__ unsigned short f2bf(float f) {
    // RNE float -> bf16 (inputs are finite normals; no NaN handling needed)
    unsigned u = __builtin_bit_cast(unsigned, f);
    u += 0x7FFFu + ((u >> 16) & 1u);
    return (unsigned short)(u >> 16);
}

// ---------- fused conversion + row-sq + colsum partials ----------
// 256 blocks x 256 threads; block covers 32 rows (8 rows per wave).
// Deterministic: all reductions fixed-order, no atomics.
__global__ void k_conv(const float* __restrict__ src, const float* __restrict__ tgt,
                       short* __restrict__ bfall, float* __restrict__ sq,
                       float* __restrict__ cspart) {
    __shared__ float colp[4][NCOLS];
    int t = threadIdx.x, w = t >> 6, l = t & 63;
    int r0 = blockIdx.x * 32 + w * 8;
    float c0x=0.f,c0y=0.f,c0z=0.f,c0w=0.f, c1x=0.f,c1y=0.f,c1z=0.f,c1w=0.f;
    #pragma unroll
    for (int r = 0; r < 8; ++r) {
        int row = r0 + r;
        const float* base = (row < BHALF) ? (src + (size_t)row * NCOLS)
                                          : (tgt + (size_t)(row - BHALF) * NCOLS);
        float4 a = ((const float4*)base)[2 * l];
        float4 b = ((const float4*)base)[2 * l + 1];
        s16x8 v;
        v[0] = (short)f2bf(a.x); v[1] = (short)f2bf(a.y);
        v[2] = (short)f2bf(a.z); v[3] = (short)f2bf(a.w);
        v[4] = (short)f2bf(b.x); v[5] = (short)f2bf(b.y);
        v[6] = (short)f2bf(b.z); v[7] = (short)f2bf(b.w);
        ((s16x8*)(bfall + (size_t)row * NCOLS))[l] = v;
        float s = a.x*a.x + a.y*a.y + a.z*a.z + a.w*a.w
                + b.x*b.x + b.y*b.y + b.z*b.z + b.w*b.w;
        #pragma unroll
        for (int o = 32; o > 0; o >>= 1) s += __shfl_down(s, o);
        if (l == 0) sq[row] = s;
        c0x += a.x; c0y += a.y; c0z += a.z; c0w += a.w;
        c1x += b.x; c1y += b.y; c1z += b.z; c1w += b.w;
    }
    colp[w][l*8+0] = c0x; colp[w][l*8+1] = c0y; colp[w][l*8+2] = c0z; colp[w][l*8+3] = c0w;
    colp[w][l*8+4] = c1x; colp[w][l*8+5] = c1y; colp[w][l*8+6] = c1z; colp[w][l*8+7] = c1w;
    __syncthreads();
    float s0 = colp[0][t] + colp[1][t] + colp[2][t] + colp[3][t];
    float s1 = colp[0][t+256] + colp[1][t+256] + colp[2][t+256] + colp[3][t+256];
    cspart[(size_t)blockIdx.x * NCOLS + t]       = s0;
    cspart[(size_t)blockIdx.x * NCOLS + t + 256] = s1;
}

// bandwidth from analytic sum(l2) = 2n*T - 2*||colsum||^2 ; store log2(e)/bw_k.
// 1024 threads, independent accumulator chains, fixed-order -> deterministic.
__global__ void k_bw(const float* __restrict__ sq, const float* __restrict__ cspart,
                     float* __restrict__ cvals) {
    __shared__ double red[1024];
    int t = threadIdx.x;
    // phase 1: sum of sq (8 independent loads per thread)
    double a = 0.0;
    #pragma unroll
    for (int i = 0; i < 8; ++i) a += (double)sq[t + i * 1024];
    red[t] = a; __syncthreads();
    for (int o = 512; o > 0; o >>= 1) { if (t < o) red[t] += red[t + o]; __syncthreads(); }
    double sT = red[0];
    __syncthreads();
    // phase 2: colsum over 256 partials; thread t: col c = t&511, half h = t>>9
    int c = t & 511, h = t >> 9;
    double d0 = 0.0, d1 = 0.0, d2 = 0.0, d3 = 0.0;
    int p0 = h * 128;
    #pragma unroll 8
    for (int p = 0; p < 128; p += 4) {
        d0 += (double)cspart[(size_t)(p0 + p + 0) * NCOLS + c];
        d1 += (double)cspart[(size_t)(p0 + p + 1) * NCOLS + c];
        d2 += (double)cspart[(size_t)(p0 + p + 2) * NCOLS + c];
        d3 += (double)cspart[(size_t)(p0 + p + 3) * NCOLS + c];
    }
    red[t] = (d0 + d1) + (d2 + d3);
    __syncthreads();
    double v = 0.0;
    if (t < 512) { double cs = red[t] + red[t + 512]; v = cs * cs; }
    __syncthreads();
    red[t] = v; __syncthreads();
    for (int o = 512; o > 0; o >>= 1) { if (t < o) red[t] += red[t + o]; __syncthreads(); }
    if (t == 0) {
        double G = red[0];
        double sum_l2 = 2.0 * (double)NROWS * sT - 2.0 * G;
        double denom = (double)NROWS * (double)NROWS - (double)NROWS;
        double bw = sum_l2 / denom / 4.0;   // KERNEL_MUL^(KERNEL_NUM/2) = 4
        const double L2E = 1.4426950408889634;
        double b = bw;
        #pragma unroll
        for (int k = 0; k < 5; ++k) { cvals[k] = (float)(L2E / b); b *= 2.0; }
    }
}

// ---------- main fused MMD kernel ----------
// 256x128 tile per block, 8 waves (4x2), per-wave 64x64 via 4x4 of 16x16x32 MFMA
// (per-wave step byte-identical to R9's proven structure). 3 LDS buffers
// (A 16KB + B 8KB each = 72 KB), counted vmcnt(3), vmcnt->barrier->stage->compute.
// launch_bounds(512,4) caps regs at 128 -> 2 blocks/CU x 8 waves = 4 waves/SIMD
// (2x R9 occupancy). n-outer MFMA order keeps frag regs ~24 (fit under 128).
// Triangular tiles over 32x64 grid (tj >= 2*ti); per-element diag weights for
// tj in {2ti, 2ti+1}. Deterministic psum, no atomics.
__global__ __launch_bounds__(512, 4)
void k_mmd(const short* __restrict__ bfall, const float* __restrict__ sq,
           const float* __restrict__ cvals, double* __restrict__ psum) {
    __shared__ short As[3][BM * BK];   // 3 x 16 KB
    __shared__ short Bs[3][BN * BK];   // 3 x 8 KB
    __shared__ float wred[8];

    // T1: XCD-aware bijective swizzle (NBLK = 8*132), then triangular decode
    int bid = blockIdx.x;
    int swz = (bid & 7) * (NBLK / 8) + (bid >> 3);
    int rem = swz;
    int ti = 0;
    while (rem >= NTJ - 2 * ti) { rem -= NTJ - 2 * ti; ++ti; }
    int tj = 2 * ti + rem;

    const int t  = threadIdx.x;  // 0..511
    const int w  = t >> 6;       // wave 0..7
    const int l  = t & 63;
    const int wr = w >> 1, wc = w & 1;   // 4x2 wave grid
    const int lr = l & 15;       // fragment row/col lane
    const int lk = l >> 4;       // 0..3 k-group (8 bf16 = 1 slot each)

    const int rowA0 = ti * BM, rowB0 = tj * BN;
    const short* gA = bfall + (size_t)rowA0 * NCOLS;
    const short* gB = bfall + (size_t)rowB0 * NCOLS;

    // ---- hoisted staging addresses ----
    // A tile = 1024 16B-chunks: thread t handles q=t and q=t+512; B = 512: q=t.
    // chunk q -> row=q>>2, slot=q&3, swizzled ss = slot^((row>>1)&3).
    // Second A chunk: row+128 -> same ss (128>>1=64 == 0 mod 4) -> ga1 = ga0+128*NCOLS.
    const int row0 = t >> 2, ss0 = (t & 3) ^ ((row0 >> 1) & 3);
    const short* ga0 = gA + (size_t)row0 * NCOLS + ss0 * 8;
    const short* ga1 = ga0 + (size_t)128 * NCOLS;
    const short* gb0 = gB + (size_t)row0 * NCOLS + ss0 * 8;
    char* dA = (char*)As + t * 16;   // chunk t dest; chunk t+512 dest = dA + 8192
    char* dB = (char*)Bs + t * 16;

    // ---- hoisted compute addresses (ssl m-independent; bsel/m as const imm) ----
    const int ssl  = lk ^ ((lr >> 1) & 3);
    const char* pA = (const char*)As + (wr * 64 + lr) * 64 + ssl * 16;
    const char* pB = (const char*)Bs + (wc * 64 + lr) * 64 + ssl * 16;

    // stage tile kt into buffer bsel: 3 global_load_lds per wave -> vmcnt +3
    #define STAGE(bsel, kt)                                                        \
        __builtin_amdgcn_global_load_lds((guint*)(ga0 + (kt) * BK),                \
            (luint*)(dA + (bsel) * 16384), 16, 0, 0);                              \
        __builtin_amdgcn_global_load_lds((guint*)(ga1 + (kt) * BK),                \
            (luint*)(dA + (bsel) * 16384 + 8192), 16, 0, 0);                       \
        __builtin_amdgcn_global_load_lds((guint*)(gb0 + (kt) * BK),                \
            (luint*)(dB + (bsel) * 8192), 16, 0, 0);

    // compute one K-step from buffer bsel: 8 ds_read_b128 + 16 MFMA per wave.
    // n-outer order: bf read per n keeps live frag regs ~24 (128-reg budget).
    #define COMPUTE(bsel)                                                          \
        {                                                                          \
            s16x8 af[4];                                                           \
            _Pragma("unroll")                                                      \
            for (int m = 0; m < 4; ++m)                                            \
                af[m] = *(const s16x8*)(pA + (bsel) * 16384 + m * 1024);           \
            __builtin_amdgcn_s_setprio(1);                                         \
            _Pragma("unroll")                                                      \
            for (int n = 0; n < 4; ++n) {                                          \
                s16x8 bfn = *(const s16x8*)(pB + (bsel) * 8192 + n * 1024);        \
                _Pragma("unroll")                                                  \
                for (int m = 0; m < 4; ++m)                                        \
                    acc[m][n] = __builtin_amdgcn_mfma_f32_16x16x32_bf16(           \
                        af[m], bfn, acc[m][n], 0, 0, 0);                           \
            }                                                                      \
            __builtin_amdgcn_s_setprio(0);                                         \
        }

    // step kt: wait own stage(kt) landed (kt+1's 3 stay in flight), barrier
    // certifies all waves' stage(kt) landed + buffer (kt+2)%3 free, prefetch
    // kt+2, compute kt.
    #define STEP(kt, vm)                                                           \
        asm volatile("s_waitcnt vmcnt(" #vm ")" ::: "memory");                     \
        __builtin_amdgcn_s_barrier();                                              \
        asm volatile("" ::: "memory");                                             \
        if ((kt) + 2 < NKT) { STAGE(((kt) + 2) % 3, (kt) + 2) }                    \
        COMPUTE((kt) % 3)

    f32x4 acc[4][4] = {};

    STAGE(0, 0)
    STAGE(1, 1)        // 6 loads in flight

    STEP(0, 3)  STEP(1, 3)  STEP(2, 3)  STEP(3, 3)
    STEP(4, 3)  STEP(5, 3)  STEP(6, 3)  STEP(7, 3)
    STEP(8, 3)  STEP(9, 3)  STEP(10, 3) STEP(11, 3)
    STEP(12, 3) STEP(13, 3) STEP(14, 3) STEP(15, 0)

    #undef STAGE
    #undef COMPUTE
    #undef STEP

    // ---------- epilogue: l2 -> exp square-chain -> signed/weighted sum ----------
    // (global loads kept AFTER the K-loop so they don't perturb vmcnt counts)
    f32x4 sqa[4];
    #pragma unroll
    for (int m = 0; m < 4; ++m)
        sqa[m] = *(const f32x4*)&sq[rowA0 + wr * 64 + m * 16 + lk * 4];
    float sqb[4];
    #pragma unroll
    for (int n = 0; n < 4; ++n)
        sqb[n] = sq[rowB0 + wc * 64 + n * 16 + lr];
    float c4 = cvals[4];

    // diag-containing tiles: tj in {2ti, 2ti+1}; others are strictly upper (gj>gi)
    const bool diag = (tj <= 2 * ti + 1);
    const float sgn = ((rowA0 < BHALF) == (rowB0 < BHALF)) ? 1.f : -1.f;
    float local = 0.f;
    #pragma unroll
    for (int m = 0; m < 4; ++m)
        #pragma unroll
        for (int n = 0; n < 4; ++n)
            #pragma unroll
            for (int r = 0; r < 4; ++r) {
                float d  = acc[m][n][r];
                float l2 = sqa[m][r] + sqb[n] - 2.f * d;
                // e_k = exp(-l2/(bw*2^k)) = x^(2^(4-k)), x = 2^(-l2*c4)
                float x  = exp2f(-l2 * c4);
                float x2 = x * x;
                float x4 = x2 * x2;
                float x8 = x4 * x4;
                float e  = x + x2 + x4 + x8 + x8 * x8;
                if (diag) {
                    int gi = rowA0 + wr * 64 + m * 16 + lk * 4 + r;
                    int gj = rowB0 + wc * 64 + n * 16 + lr;
                    float wgt = (gj > gi) ? 2.f : ((gj == gi) ? 1.f : 0.f);
                    local += wgt * e;
                } else {
                    local += e;
                }
            }
    if (!diag) local *= 2.f * sgn;   // diag-containing tiles always sgn=+1

    #pragma unroll
    for (int o = 32; o > 0; o >>= 1) local += __shfl_down(local, o);
    if (l == 0) wred[w] = local;
    __syncthreads();
    if (t == 0) {
        float bsum = ((wred[0] + wred[1]) + (wred[2] + wred[3]))
                   + ((wred[4] + wred[5]) + (wred[6] + wred[7]));
        psum[blockIdx.x] = (double)bsum;
    }
}

// fixed-order final reduction over NBLK partials -> loss
__global__ void k_final(const double* __restrict__ psum, float* __restrict__ out) {
    __shared__ double red[256];
    int t = threadIdx.x;
    double a = 0.0;
    for (int i = t; i < NBLK; i += 256) a += psum[i];
    red[t] = a; __syncthreads();
    for (int o = 128; o > 0; o >>= 1) { if (t < o) red[t] += red[t + o]; __syncthreads(); }
    if (t == 0) out[0] = (float)(red[0] * (1.0 / ((double)BHALF * (double)BHALF)));
}

// ---------- launch ----------
extern "C" void kernel_launch(void* const* d_in, const int* in_sizes, int n_in,
                              void* d_out, int out_size, void* d_ws, size_t ws_size,
                              hipStream_t stream) {
    (void)in_sizes; (void)n_in; (void)out_size; (void)ws_size;
    const float* src = (const float*)d_in[0];
    const float* tgt = (const float*)d_in[1];
    float* out = (float*)d_out;
    char* ws = (char*)d_ws;
    // layout (all offsets 16B-aligned; every consumed word is rewritten each call):
    short*  bfall  = (short*) (ws);                      // 8192*512*2 = 8388608 B
    float*  sq     = (float*) (ws + 8388608);            // 8192*4 = 32768 B
    float*  cspart = (float*) (ws + 8388608 + 32768);    // 256*512*4 = 524288 B
    float*  cvals  = (float*) (ws + 8388608 + 32768 + 524288);        // 20 B
    double* psum   = (double*)(ws + 8388608 + 32768 + 524288 + 32);   // 1056*8 = 8448 B

    k_conv  <<<CSPART, 256, 0, stream>>>(src, tgt, bfall, sq, cspart);
    k_bw    <<<1, 1024, 0, stream>>>(sq, cspart, cvals);
    k_mmd   <<<NBLK, 512, 0, stream>>>(bfall, sq, cvals, psum);
    k_final <<<1, 256, 0, stream>>>(psum, out);
}

// Round 12
// 79.019 us; speedup vs baseline: 1.1605x; 1.0911x over previous
//
#include <hip/hip_runtime.h>
#include <math.h>

typedef float f32x4 __attribute__((ext_vector_type(4)));
typedef short s16x8 __attribute__((ext_vector_type(8)));

#define NROWS 8192
#define NCOLS 512
#define BHALF 4096
#define NT    64       // super-rows: 8192 / 128
#define NBLK  2080     // NT*(NT+1)/2 super-tiles; 2080 % 8 == 0
#define CSPART 256     // colsum partial blocks

// ---------- helpers ----------
__device__ __forceinline__ unsigned short f2bf(float f) {
    // RNE float -> bf16 (inputs are finite normals; no NaN handling needed)
    unsigned u = __builtin_bit_cast(unsigned, f);
    u += 0x7FFFu + ((u >> 16) & 1u);
    return (unsigned short)(u >> 16);
}

// ---------- fused conversion + FRAGMENT-ORDER repack + row-sq + colsum ----------
// 256 blocks x 256 threads; block covers 32 rows (8 rows per wave).
// bfrag layout: 16-byte chunk (rowgrp g, kslot s, lane lr) at byte
// g*16384 + s*256 + lr*16, i.e. element (row = g*16+lr, k = s*8 + 0..7).
// A wave's MFMA fragment load (lanes (lk,lr), 16B each) is then one contiguous
// 1 KB line -> perfectly coalesced global_load_dwordx4, no LDS staging needed
// in the GEMM. Deterministic: all reductions fixed-order, no atomics.
__global__ void k_conv(const float* __restrict__ src, const float* __restrict__ tgt,
                       short* __restrict__ bfrag, float* __restrict__ sq,
                       float* __restrict__ cspart) {
    __shared__ short ldsb[32][520];    // +8 shorts pad per row
    __shared__ float colp[4][NCOLS];
    int t = threadIdx.x, w = t >> 6, l = t & 63;
    int r0 = blockIdx.x * 32;
    float c0x=0.f,c0y=0.f,c0z=0.f,c0w=0.f, c1x=0.f,c1y=0.f,c1z=0.f,c1w=0.f;
    #pragma unroll
    for (int r = 0; r < 8; ++r) {
        int row = r0 + w * 8 + r;
        const float* base = (row < BHALF) ? (src + (size_t)row * NCOLS)
                                          : (tgt + (size_t)(row - BHALF) * NCOLS);
        float4 a = ((const float4*)base)[2 * l];
        float4 b = ((const float4*)base)[2 * l + 1];
        s16x8 v;
        v[0] = (short)f2bf(a.x); v[1] = (short)f2bf(a.y);
        v[2] = (short)f2bf(a.z); v[3] = (short)f2bf(a.w);
        v[4] = (short)f2bf(b.x); v[5] = (short)f2bf(b.y);
        v[6] = (short)f2bf(b.z); v[7] = (short)f2bf(b.w);
        *(s16x8*)&ldsb[w * 8 + r][l * 8] = v;
        float s = a.x*a.x + a.y*a.y + a.z*a.z + a.w*a.w
                + b.x*b.x + b.y*b.y + b.z*b.z + b.w*b.w;
        #pragma unroll
        for (int o = 32; o > 0; o >>= 1) s += __shfl_down(s, o);
        if (l == 0) sq[row] = s;
        c0x += a.x; c0y += a.y; c0z += a.z; c0w += a.w;
        c1x += b.x; c1y += b.y; c1z += b.z; c1w += b.w;
    }
    colp[w][l*8+0] = c0x; colp[w][l*8+1] = c0y; colp[w][l*8+2] = c0z; colp[w][l*8+3] = c0w;
    colp[w][l*8+4] = c1x; colp[w][l*8+5] = c1y; colp[w][l*8+6] = c1z; colp[w][l*8+7] = c1w;
    __syncthreads();
    float s0 = colp[0][t] + colp[1][t] + colp[2][t] + colp[3][t];
    float s1 = colp[0][t+256] + colp[1][t+256] + colp[2][t+256] + colp[3][t+256];
    cspart[(size_t)blockIdx.x * NCOLS + t]       = s0;
    cspart[(size_t)blockIdx.x * NCOLS + t + 256] = s1;
    // repack out: 2 rowgrps x 64 slots x 16 lanes = 2048 chunks, 8 per thread;
    // writes are contiguous per wave (lr fastest) -> coalesced.
    int rg0 = r0 >> 4;
    #pragma unroll
    for (int c8 = 0; c8 < 8; ++c8) {
        int c = c8 * 256 + t;
        int g = c >> 10, s = (c >> 4) & 63, lrr = c & 15;
        s16x8 v = *(const s16x8*)&ldsb[g * 16 + lrr][s * 8];
        *(s16x8*)(bfrag + (size_t)(rg0 + g) * 8192 + s * 128 + lrr * 8) = v;
    }
}

// bandwidth from analytic sum(l2) = 2n*T - 2*||colsum||^2 ; store log2(e)/bw_k.
// 1024 threads, independent accumulator chains, fixed-order -> deterministic.
__global__ void k_bw(const float* __restrict__ sq, const float* __restrict__ cspart,
                     float* __restrict__ cvals) {
    __shared__ double red[1024];
    int t = threadIdx.x;
    double a = 0.0;
    #pragma unroll
    for (int i = 0; i < 8; ++i) a += (double)sq[t + i * 1024];
    red[t] = a; __syncthreads();
    for (int o = 512; o > 0; o >>= 1) { if (t < o) red[t] += red[t + o]; __syncthreads(); }
    double sT = red[0];
    __syncthreads();
    int c = t & 511, h = t >> 9;
    double d0 = 0.0, d1 = 0.0, d2 = 0.0, d3 = 0.0;
    int p0 = h * 128;
    #pragma unroll 8
    for (int p = 0; p < 128; p += 4) {
        d0 += (double)cspart[(size_t)(p0 + p + 0) * NCOLS + c];
        d1 += (double)cspart[(size_t)(p0 + p + 1) * NCOLS + c];
        d2 += (double)cspart[(size_t)(p0 + p + 2) * NCOLS + c];
        d3 += (double)cspart[(size_t)(p0 + p + 3) * NCOLS + c];
    }
    red[t] = (d0 + d1) + (d2 + d3);
    __syncthreads();
    double v = 0.0;
    if (t < 512) { double cs = red[t] + red[t + 512]; v = cs * cs; }
    __syncthreads();
    red[t] = v; __syncthreads();
    for (int o = 512; o > 0; o >>= 1) { if (t < o) red[t] += red[t + o]; __syncthreads(); }
    if (t == 0) {
        double G = red[0];
        double sum_l2 = 2.0 * (double)NROWS * sT - 2.0 * G;
        double denom = (double)NROWS * (double)NROWS - (double)NROWS;
        double bw = sum_l2 / denom / 4.0;   // KERNEL_MUL^(KERNEL_NUM/2) = 4
        const double L2E = 1.4426950408889634;
        double b = bw;
        #pragma unroll
        for (int k = 0; k < 5; ++k) { cvals[k] = (float)(L2E / b); b *= 2.0; }
    }
}

// ---------- main fused MMD kernel: barrier-free fragment streaming ----------
// Each wave owns a 64x64 tile (4x4 of 16x16x32 MFMA, acc 64 AGPR). Fragments
// loaded DIRECTLY from the repacked global matrix (coalesced 1KB/load, L2/L3-
// resident, 8.4 MB total), no LDS, no barriers in the K-loop -> compiler
// software-pipelines freely. Block = 2x2 super-tile of wave-tiles (L1 reuse:
// wave pairs share fragment addresses). Super-triangle over 128-row tiles:
// super (I,J), J>=I; diag supers: waves {(2I,2I) elem, (2I,2I+1) w=1,
// (2I+1,2I+1) elem, (2I,2I+1) w=1} -- the duplicate pair sums to weight 2
// exactly, no idle waves. Deterministic psum, no atomics.
__global__ __launch_bounds__(256, 3)
void k_mmd(const short* __restrict__ bfrag, const float* __restrict__ sq,
           const float* __restrict__ cvals, double* __restrict__ psum) {
    __shared__ float wred[4];

    // T1: XCD-aware bijective swizzle (NBLK = 8*260), then triangular decode
    int bid = blockIdx.x;
    int swz = (bid & 7) * (NBLK / 8) + (bid >> 3);
    int rem = swz;
    int I = 0;
    while (rem >= NT - I) { rem -= NT - I; ++I; }
    int J = I + rem;

    const int t  = threadIdx.x;
    const int w  = t >> 6;       // wave 0..3
    const int l  = t & 63;
    const int lr = l & 15;
    const int lk = l >> 4;

    // wave -> tile assignment within the 2x2 super-tile
    const bool dsup = (I == J);
    int da, db;
    if (dsup) { da = (w == 2) ? 1 : 0; db = (w == 0) ? 0 : 1; }
    else      { da = w >> 1;           db = w & 1; }
    const int i_t = 2 * I + da, j_t = 2 * J + db;
    const int rowA0 = i_t * 64, rowB0 = j_t * 64;

    // fragment bases: chunk(rowgrp, s, lr) at rowgrp*16384 + s*256 + lr*16 bytes
    const int lko = lk * 256 + lr * 16;
    const char* pa = (const char*)bfrag + ((size_t)(i_t * 4) << 14) + lko;
    const char* pb = (const char*)bfrag + ((size_t)(j_t * 4) << 14) + lko;

    f32x4 acc[4][4] = {};
    #pragma unroll
    for (int kt = 0; kt < 16; ++kt) {
        s16x8 af[4], bf[4];
        #pragma unroll
        for (int m = 0; m < 4; ++m)
            af[m] = *(const s16x8*)(pa + m * 16384 + kt * 1024);
        #pragma unroll
        for (int n = 0; n < 4; ++n)
            bf[n] = *(const s16x8*)(pb + n * 16384 + kt * 1024);
        __builtin_amdgcn_s_setprio(1);
        #pragma unroll
        for (int m = 0; m < 4; ++m)
            #pragma unroll
            for (int n = 0; n < 4; ++n)
                acc[m][n] = __builtin_amdgcn_mfma_f32_16x16x32_bf16(
                    af[m], bf[n], acc[m][n], 0, 0, 0);
        __builtin_amdgcn_s_setprio(0);
    }

    // ---------- epilogue: l2 -> exp square-chain -> signed/weighted sum ----------
    f32x4 sqa[4];
    #pragma unroll
    for (int m = 0; m < 4; ++m)
        sqa[m] = *(const f32x4*)&sq[rowA0 + m * 16 + lk * 4];
    float sqb[4];
    #pragma unroll
    for (int n = 0; n < 4; ++n)
        sqb[n] = sq[rowB0 + n * 16 + lr];
    float c4 = cvals[4];

    const bool elem = dsup && ((w & 1) == 0);        // elementwise-diag tiles
    const float wb  = dsup ? 1.f : 2.f;              // pair weight (dup tiles sum to 2)
    const float sgn = ((rowA0 < BHALF) == (rowB0 < BHALF)) ? 1.f : -1.f;
    float local = 0.f;
    #pragma unroll
    for (int m = 0; m < 4; ++m)
        #pragma unroll
        for (int n = 0; n < 4; ++n)
            #pragma unroll
            for (int r = 0; r < 4; ++r) {
                float d  = acc[m][n][r];
                float l2 = sqa[m][r] + sqb[n] - 2.f * d;
                // e_k = exp(-l2/(bw*2^k)) = x^(2^(4-k)), x = 2^(-l2*c4)
                float x  = exp2f(-l2 * c4);
                float x2 = x * x;
                float x4 = x2 * x2;
                float x8 = x4 * x4;
                float e  = x + x2 + x4 + x8 + x8 * x8;
                if (elem) {
                    int gi = rowA0 + m * 16 + lk * 4 + r;
                    int gj = rowB0 + n * 16 + lr;
                    float wgt = (gj > gi) ? 2.f : ((gj == gi) ? 1.f : 0.f);
                    local += wgt * e;
                } else {
                    local += e;
                }
            }
    if (!elem) local *= wb * sgn;   // dsup non-elem tiles: wb=1, sgn=+1

    #pragma unroll
    for (int o = 32; o > 0; o >>= 1) local += __shfl_down(local, o);
    if (l == 0) wred[w] = local;
    __syncthreads();
    if (t == 0) {
        psum[blockIdx.x] = (double)((wred[0] + wred[1]) + (wred[2] + wred[3]));
    }
}

// fixed-order final reduction over NBLK partials -> loss
__global__ void k_final(const double* __restrict__ psum, float* __restrict__ out) {
    __shared__ double red[256];
    int t = threadIdx.x;
    double a = 0.0;
    for (int i = t; i < NBLK; i += 256) a += psum[i];
    red[t] = a; __syncthreads();
    for (int o = 128; o > 0; o >>= 1) { if (t < o) red[t] += red[t + o]; __syncthreads(); }
    if (t == 0) out[0] = (float)(red[0] * (1.0 / ((double)BHALF * (double)BHALF)));
}

// ---------- launch ----------
extern "C" void kernel_launch(void* const* d_in, const int* in_sizes, int n_in,
                              void* d_out, int out_size, void* d_ws, size_t ws_size,
                              hipStream_t stream) {
    (void)in_sizes; (void)n_in; (void)out_size; (void)ws_size;
    const float* src = (const float*)d_in[0];
    const float* tgt = (const float*)d_in[1];
    float* out = (float*)d_out;
    char* ws = (char*)d_ws;
    // layout (all offsets 16B-aligned; every consumed word is rewritten each call):
    short*  bfrag  = (short*) (ws);                      // 8192*512*2 = 8388608 B
    float*  sq     = (float*) (ws + 8388608);            // 8192*4 = 32768 B
    float*  cspart = (float*) (ws + 8388608 + 32768);    // 256*512*4 = 524288 B
    float*  cvals  = (float*) (ws + 8388608 + 32768 + 524288);        // 20 B
    double* psum   = (double*)(ws + 8388608 + 32768 + 524288 + 32);   // 2080*8 = 16640 B

    k_conv  <<<CSPART, 256, 0, stream>>>(src, tgt, bfrag, sq, cspart);
    k_bw    <<<1, 1024, 0, stream>>>(sq, cspart, cvals);
    k_mmd   <<<NBLK, 256, 0, stream>>>(bfrag, sq, cvals, psum);
    k_final <<<1, 256, 0, stream>>>(psum, out);
}